// Round 1
// baseline (797.572 us; speedup 1.0000x reference)
//
#include <hip/hip_runtime.h>

namespace {

constexpr int B = 16, S = 1024, M = 4096, C = 768, D = 256;

// ---------------------------------------------------------------------------
// Kernel 1: nearest-neighbor argmin over M points per (b, seed).
// Bit-exact replication of the reference distance formula (no FMA contraction)
// so that argmin ties/near-ties resolve identically to the numpy reference.
// Block = 256 threads handles 16 seeds; 16 lanes per seed.
// ---------------------------------------------------------------------------
__global__ __launch_bounds__(256)
void nn_kernel(const float* __restrict__ xyz, const float* __restrict__ p,
               int* __restrict__ idx_out) {
  const int b = blockIdx.y;
  const int t = threadIdx.x;
  const int seed = blockIdx.x * 16 + (t >> 4);
  const int l16 = t & 15;

  const float sx = xyz[((size_t)b * S + seed) * 3 + 0];
  const float sy = xyz[((size_t)b * S + seed) * 3 + 1];
  const float sz = xyz[((size_t)b * S + seed) * 3 + 2];
  const float ss = __fadd_rn(__fadd_rn(__fmul_rn(sx, sx), __fmul_rn(sy, sy)),
                             __fmul_rn(sz, sz));

  __shared__ float px[256], py[256], pz[256], pp[256];

  float best = 3.4028235e38f;
  int besti = 0;
  const float* pb = p + (size_t)b * M * 3;

  for (int m0 = 0; m0 < M; m0 += 256) {
    __syncthreads();
    {
      const float a0 = pb[(size_t)(m0 + t) * 3 + 0];
      const float a1 = pb[(size_t)(m0 + t) * 3 + 1];
      const float a2 = pb[(size_t)(m0 + t) * 3 + 2];
      px[t] = a0; py[t] = a1; pz[t] = a2;
      pp[t] = __fadd_rn(__fadd_rn(__fmul_rn(a0, a0), __fmul_rn(a1, a1)),
                        __fmul_rn(a2, a2));
    }
    __syncthreads();
    #pragma unroll 4
    for (int j = l16; j < 256; j += 16) {
      float dot = __fmul_rn(sx, px[j]);
      dot = __fadd_rn(dot, __fmul_rn(sy, py[j]));
      dot = __fadd_rn(dot, __fmul_rn(sz, pz[j]));
      const float d2 = __fadd_rn(__fsub_rn(ss, __fmul_rn(2.0f, dot)), pp[j]);
      const int mi = m0 + j;
      // strictly-less keeps the first occurrence within this thread's
      // (increasing-index) subset
      if (d2 < best || (d2 == best && mi < besti)) { best = d2; besti = mi; }
    }
  }
  // lexicographic (d2, idx) min across the 16 lanes of this seed
  #pragma unroll
  for (int off = 8; off >= 1; off >>= 1) {
    const float ob = __shfl_xor(best, off, 16);
    const int   oi = __shfl_xor(besti, off, 16);
    if (ob < best || (ob == best && oi < besti)) { best = ob; besti = oi; }
  }
  if (l16 == 0) idx_out[b * S + seed] = besti;
}

// ---------------------------------------------------------------------------
// Kernel 2: gather f_last[b, :, idx[b,s]] (column of C=768) + LayerNorm over C.
// One block per (b, s). Output layout [B][S][C] (coalesced stores).
// ---------------------------------------------------------------------------
__global__ __launch_bounds__(256)
void gather_ln_kernel(const float* __restrict__ f, const int* __restrict__ idx,
                      const float* __restrict__ gamma, const float* __restrict__ beta,
                      float* __restrict__ xln) {
  const int b = blockIdx.y;
  const int s = blockIdx.x;
  const int t = threadIdx.x;
  const int m = idx[b * S + s];

  const float* fb = f + (size_t)b * C * M + m;
  const float v0 = fb[(size_t)(t      ) * M];
  const float v1 = fb[(size_t)(t + 256) * M];
  const float v2 = fb[(size_t)(t + 512) * M];

  __shared__ float red[4];
  __shared__ float stats[2];
  const int wave = t >> 6;

  float ps = v0 + v1 + v2;
  #pragma unroll
  for (int off = 32; off >= 1; off >>= 1) ps += __shfl_xor(ps, off);
  if ((t & 63) == 0) red[wave] = ps;
  __syncthreads();
  if (t == 0) stats[0] = (red[0] + red[1] + red[2] + red[3]) * (1.0f / 768.0f);
  __syncthreads();
  const float mu = stats[0];

  const float d0 = v0 - mu, d1 = v1 - mu, d2 = v2 - mu;
  float pv = d0 * d0 + d1 * d1 + d2 * d2;
  #pragma unroll
  for (int off = 32; off >= 1; off >>= 1) pv += __shfl_xor(pv, off);
  if ((t & 63) == 0) red[wave] = pv;
  __syncthreads();
  if (t == 0) {
    const float var = (red[0] + red[1] + red[2] + red[3]) * (1.0f / 768.0f);
    stats[1] = 1.0f / sqrtf(var + 1e-5f);
  }
  __syncthreads();
  const float rs = stats[1];

  float* ob = xln + ((size_t)b * S + s) * C;
  ob[t      ] = (d0 * rs) * gamma[t      ] + beta[t      ];
  ob[t + 256] = (d1 * rs) * gamma[t + 256] + beta[t + 256];
  ob[t + 512] = (d2 * rs) * gamma[t + 512] + beta[t + 512];
}

// ---------------------------------------------------------------------------
// Kernel 3: tiled fp32 GEMM  out[b,o,s] = act( sum_c W1[o,c] A1[b,c,s]
//                                            (+ sum_c W2[o,c] A2[b,c,s]) + bias[o] )
// A layout 0 = CS (A[c*ldA + s]),  1 = SC (A[s*ldA + c]).
// 64x64 output tile, K-chunk 16, 256 threads, 4x4 micro-tile per thread.
// ---------------------------------------------------------------------------
__global__ __launch_bounds__(256)
void gemm_kernel(const float* __restrict__ W1, int ldw1, int K1,
                 const float* __restrict__ A1, int layoutA1, int ldA1, size_t strideA1,
                 const float* __restrict__ W2, int ldw2, int K2,
                 const float* __restrict__ A2, int layoutA2, int ldA2, size_t strideA2,
                 const float* __restrict__ bias, float* __restrict__ out,
                 size_t strideOut, int doRelu) {
  const int b  = blockIdx.z;
  const int s0 = blockIdx.x * 64;
  const int o0 = blockIdx.y * 64;
  const int t  = threadIdx.x;
  const int tx = t & 15;   // 16 column groups (4 cols each)
  const int ty = t >> 4;   // 16 row groups   (4 rows each)

  __shared__ float Wt[16][68];  // [kc][o_local], stride 68 -> 16B aligned rows, 2-way bank alias (free)
  __shared__ float Xt[16][68];  // [kc][s_local]

  float acc[4][4] = {{0.f}};

  for (int pass = 0; pass < 2; ++pass) {
    const float* W = pass ? W2 : W1;
    if (W == nullptr) break;
    const int ldw      = pass ? ldw2 : ldw1;
    const int K        = pass ? K2 : K1;
    const int layoutA  = pass ? layoutA2 : layoutA1;
    const int ldA      = pass ? ldA2 : ldA1;
    const float* Ab    = (pass ? A2 : A1) + (size_t)b * (pass ? strideA2 : strideA1);

    for (int c0 = 0; c0 < K; c0 += 16) {
      __syncthreads();
      // --- stage W tile: Wt[kc][ol] = W[(o0+ol)*ldw + c0+kc] ---
      {
        const int kc = t & 15;
        const int ol = t >> 4;
        #pragma unroll
        for (int q = 0; q < 4; ++q)
          Wt[kc][ol + 16 * q] = W[(size_t)(o0 + ol + 16 * q) * ldw + c0 + kc];
      }
      // --- stage A tile: Xt[kc][sl] ---
      if (layoutA == 0) {  // CS
        const int sl = t & 63;
        const int kr = t >> 6;
        #pragma unroll
        for (int q = 0; q < 4; ++q)
          Xt[kr + 4 * q][sl] = Ab[(size_t)(c0 + kr + 4 * q) * ldA + s0 + sl];
      } else {             // SC
        const int kc = t & 15;
        const int sl = t >> 4;
        #pragma unroll
        for (int q = 0; q < 4; ++q)
          Xt[kc][sl + 16 * q] = Ab[(size_t)(s0 + sl + 16 * q) * ldA + c0 + kc];
      }
      __syncthreads();
      // --- compute ---
      #pragma unroll
      for (int kc = 0; kc < 16; ++kc) {
        const float4 wv = *(const float4*)&Wt[kc][ty * 4];
        const float4 xv = *(const float4*)&Xt[kc][tx * 4];
        acc[0][0] += wv.x * xv.x; acc[0][1] += wv.x * xv.y; acc[0][2] += wv.x * xv.z; acc[0][3] += wv.x * xv.w;
        acc[1][0] += wv.y * xv.x; acc[1][1] += wv.y * xv.y; acc[1][2] += wv.y * xv.z; acc[1][3] += wv.y * xv.w;
        acc[2][0] += wv.z * xv.x; acc[2][1] += wv.z * xv.y; acc[2][2] += wv.z * xv.z; acc[2][3] += wv.z * xv.w;
        acc[3][0] += wv.w * xv.x; acc[3][1] += wv.w * xv.y; acc[3][2] += wv.w * xv.z; acc[3][3] += wv.w * xv.w;
      }
    }
  }

  // --- epilogue ---
  #pragma unroll
  for (int i = 0; i < 4; ++i) {
    const int o = o0 + ty * 4 + i;
    const float bi = bias ? bias[o] : 0.0f;
    float4 r;
    r.x = acc[i][0] + bi; r.y = acc[i][1] + bi; r.z = acc[i][2] + bi; r.w = acc[i][3] + bi;
    if (doRelu) {
      r.x = fmaxf(r.x, 0.f); r.y = fmaxf(r.y, 0.f);
      r.z = fmaxf(r.z, 0.f); r.w = fmaxf(r.w, 0.f);
    }
    *(float4*)&out[(size_t)b * strideOut + (size_t)o * S + s0 + tx * 4] = r;
  }
}

}  // namespace

extern "C" void kernel_launch(void* const* d_in, const int* in_sizes, int n_in,
                              void* d_out, int out_size, void* d_ws, size_t ws_size,
                              hipStream_t stream) {
  const float* seed_xyz  = (const float*)d_in[0];   // [B,S,3]
  const float* p_last    = (const float*)d_in[1];   // [B,M,3]
  const float* f_last    = (const float*)d_in[2];   // [B,C,M]
  const float* seed_feat = (const float*)d_in[3];   // [B,D,S]
  const float* ln_gamma  = (const float*)d_in[4];   // [C]
  const float* ln_beta   = (const float*)d_in[5];   // [C]
  const float* proj_w    = (const float*)d_in[6];   // [D,C]
  const float* proj_b    = (const float*)d_in[7];   // [D]
  const float* mlp_w1    = (const float*)d_in[8];   // [2D,2D]
  const float* mlp_b1    = (const float*)d_in[9];   // [2D]
  const float* mlp_w2    = (const float*)d_in[10];  // [D,2D]
  const float* mlp_b2    = (const float*)d_in[11];  // [2D]? -> [D]
  float* out = (float*)d_out;                       // [B,D,S]

  // workspace layout (65 MB):
  //   [0,1MB)        : idx  [B*S] int
  //   [1MB, 1+48MB)  : xln  [B][S][C] fp32   -- later aliased by h [B][512][S] (32MB)
  //   [49MB, 65MB)   : proj [B][D][S] fp32   (16MB)
  char* ws = (char*)d_ws;
  int*   idx  = (int*)ws;
  float* xln  = (float*)(ws + (1u << 20));
  float* proj = xln + (size_t)B * S * C;
  float* hbuf = xln;  // alias: xln dead once proj is computed

  // 1) nearest neighbor
  nn_kernel<<<dim3(S / 16, B), 256, 0, stream>>>(seed_xyz, p_last, idx);

  // 2) gather + layernorm -> xln [B][S][C]
  gather_ln_kernel<<<dim3(S, B), 256, 0, stream>>>(f_last, idx, ln_gamma, ln_beta, xln);

  // 3) proj = relu(proj_w @ xln + proj_b) -> [B][D][S]
  gemm_kernel<<<dim3(S / 64, D / 64, B), 256, 0, stream>>>(
      proj_w, C, C, xln, /*SC*/ 1, C, (size_t)S * C,
      nullptr, 0, 0, nullptr, 0, 0, 0,
      proj_b, proj, (size_t)D * S, 1);

  // 4) h = relu(W1[:, :256] @ seed_feat + W1[:, 256:] @ proj + b1) -> [B][512][S]
  gemm_kernel<<<dim3(S / 64, (2 * D) / 64, B), 256, 0, stream>>>(
      mlp_w1, 2 * D, D, seed_feat, /*CS*/ 0, S, (size_t)D * S,
      mlp_w1 + D, 2 * D, D, proj, /*CS*/ 0, S, (size_t)D * S,
      mlp_b1, hbuf, (size_t)2 * D * S, 1);

  // 5) out = W2 @ h + b2 -> [B][D][S]
  gemm_kernel<<<dim3(S / 64, D / 64, B), 256, 0, stream>>>(
      mlp_w2, 2 * D, 2 * D, hbuf, /*CS*/ 0, S, (size_t)2 * D * S,
      nullptr, 0, 0, nullptr, 0, 0, 0,
      mlp_b2, out, (size_t)D * S, 0);
}

// Round 3
// 434.919 us; speedup vs baseline: 1.8338x; 1.8338x over previous
//
#include <hip/hip_runtime.h>

namespace {

constexpr int B = 16, S = 1024, M = 4096, C = 768, D = 256;

typedef __attribute__((ext_vector_type(8))) short bf16x8;
typedef __attribute__((ext_vector_type(4))) float f32x4;

__device__ inline ushort f2bf(float f) {
  uint u = __float_as_uint(f);
  uint r = (u + 0x7FFFu + ((u >> 16) & 1u)) >> 16;
  return (ushort)r;
}

// ---------------------------------------------------------------------------
// Kernel 1: nearest-neighbor argmin (bit-exact reference distance formula).
// ---------------------------------------------------------------------------
__global__ __launch_bounds__(256)
void nn_kernel(const float* __restrict__ xyz, const float* __restrict__ p,
               int* __restrict__ idx_out) {
  const int b = blockIdx.y;
  const int t = threadIdx.x;
  const int seed = blockIdx.x * 16 + (t >> 4);
  const int l16 = t & 15;

  const float sx = xyz[((size_t)b * S + seed) * 3 + 0];
  const float sy = xyz[((size_t)b * S + seed) * 3 + 1];
  const float sz = xyz[((size_t)b * S + seed) * 3 + 2];
  const float ss = __fadd_rn(__fadd_rn(__fmul_rn(sx, sx), __fmul_rn(sy, sy)),
                             __fmul_rn(sz, sz));

  __shared__ float px[256], py[256], pz[256], pp[256];

  float best = 3.4028235e38f;
  int besti = 0;
  const float* pb = p + (size_t)b * M * 3;

  for (int m0 = 0; m0 < M; m0 += 256) {
    __syncthreads();
    {
      const float a0 = pb[(size_t)(m0 + t) * 3 + 0];
      const float a1 = pb[(size_t)(m0 + t) * 3 + 1];
      const float a2 = pb[(size_t)(m0 + t) * 3 + 2];
      px[t] = a0; py[t] = a1; pz[t] = a2;
      pp[t] = __fadd_rn(__fadd_rn(__fmul_rn(a0, a0), __fmul_rn(a1, a1)),
                        __fmul_rn(a2, a2));
    }
    __syncthreads();
    #pragma unroll 4
    for (int j = l16; j < 256; j += 16) {
      float dot = __fmul_rn(sx, px[j]);
      dot = __fadd_rn(dot, __fmul_rn(sy, py[j]));
      dot = __fadd_rn(dot, __fmul_rn(sz, pz[j]));
      const float d2 = __fadd_rn(__fsub_rn(ss, __fmul_rn(2.0f, dot)), pp[j]);
      const int mi = m0 + j;
      if (d2 < best || (d2 == best && mi < besti)) { best = d2; besti = mi; }
    }
  }
  #pragma unroll
  for (int off = 8; off >= 1; off >>= 1) {
    const float ob = __shfl_xor(best, off, 16);
    const int   oi = __shfl_xor(besti, off, 16);
    if (ob < best || (ob == best && oi < besti)) { best = ob; besti = oi; }
  }
  if (l16 == 0) idx_out[b * S + seed] = besti;
}

// ---------------------------------------------------------------------------
// Kernel 1b: per-batch bitonic sort of (idx, s) by idx — gather locality.
// ---------------------------------------------------------------------------
__global__ __launch_bounds__(512)
void sort_kernel(const int* __restrict__ idx, int* __restrict__ sIdx,
                 int* __restrict__ sS) {
  const int b = blockIdx.x;
  const int t = threadIdx.x;
  __shared__ int key[1024];
  __shared__ int val[1024];
  key[t] = idx[b * S + t];         val[t] = t;
  key[t + 512] = idx[b * S + t + 512]; val[t + 512] = t + 512;
  __syncthreads();
  for (int k = 2; k <= 1024; k <<= 1) {
    for (int j = k >> 1; j > 0; j >>= 1) {
      #pragma unroll 2
      for (int i = t; i < 1024; i += 512) {
        const int p = i ^ j;
        if (p > i) {
          const bool up = ((i & k) == 0);
          const int ki = key[i], kp = key[p];
          if ((ki > kp) == up) {
            key[i] = kp; key[p] = ki;
            const int tv = val[i]; val[i] = val[p]; val[p] = tv;
          }
        }
      }
      __syncthreads();
    }
  }
  sIdx[b * S + t] = key[t];       sS[b * S + t] = val[t];
  sIdx[b * S + t + 512] = key[t + 512]; sS[b * S + t + 512] = val[t + 512];
}

// ---------------------------------------------------------------------------
// Kernel 2: gather + LayerNorm, processed in idx-sorted rank order with
// XCD-aware swizzle (consecutive ranks -> same XCD -> L2 line reuse).
// Output bf16 [B][S][C].
// ---------------------------------------------------------------------------
__global__ __launch_bounds__(256)
void gather_ln_kernel(const float* __restrict__ f, const int* __restrict__ sIdx,
                      const int* __restrict__ sS,
                      const float* __restrict__ gamma, const float* __restrict__ beta,
                      ushort* __restrict__ xln) {
  const int b = blockIdx.y;
  const int rl = blockIdx.x;
  const int r = ((rl & 7) << 7) + (rl >> 3);   // XCD-contiguous rank mapping
  const int t = threadIdx.x;
  const int s = sS[b * S + r];
  const int m = sIdx[b * S + r];

  const float* fb = f + (size_t)b * C * M + m;
  const float v0 = fb[(size_t)(t      ) * M];
  const float v1 = fb[(size_t)(t + 256) * M];
  const float v2 = fb[(size_t)(t + 512) * M];

  __shared__ float red[4];
  __shared__ float stats[2];
  const int wave = t >> 6;

  float ps = v0 + v1 + v2;
  #pragma unroll
  for (int off = 32; off >= 1; off >>= 1) ps += __shfl_xor(ps, off);
  if ((t & 63) == 0) red[wave] = ps;
  __syncthreads();
  if (t == 0) stats[0] = (red[0] + red[1] + red[2] + red[3]) * (1.0f / 768.0f);
  __syncthreads();
  const float mu = stats[0];

  const float d0 = v0 - mu, d1 = v1 - mu, d2 = v2 - mu;
  float pv = d0 * d0 + d1 * d1 + d2 * d2;
  #pragma unroll
  for (int off = 32; off >= 1; off >>= 1) pv += __shfl_xor(pv, off);
  if ((t & 63) == 0) red[wave] = pv;
  __syncthreads();
  if (t == 0) {
    const float var = (red[0] + red[1] + red[2] + red[3]) * (1.0f / 768.0f);
    stats[1] = 1.0f / sqrtf(var + 1e-5f);
  }
  __syncthreads();
  const float rs = stats[1];

  ushort* ob = xln + ((size_t)b * S + s) * C;
  ob[t      ] = f2bf((d0 * rs) * gamma[t      ] + beta[t      ]);
  ob[t + 256] = f2bf((d1 * rs) * gamma[t + 256] + beta[t + 256]);
  ob[t + 512] = f2bf((d2 * rs) * gamma[t + 512] + beta[t + 512]);
}

// ---------------------------------------------------------------------------
// Kernel 3: transpose+convert seed_features [B][D][S] f32 -> fused[b][s][0:256] bf16
// ---------------------------------------------------------------------------
__global__ __launch_bounds__(256)
void transpose_sf_kernel(const float* __restrict__ sf, ushort* __restrict__ fused) {
  const int b = blockIdx.z;
  const int d0 = blockIdx.y * 64;
  const int s0 = blockIdx.x * 64;
  const int t = threadIdx.x;
  __shared__ float tile[64][68];

  const float* inb = sf + ((size_t)b * D + d0) * S + s0;
  #pragma unroll
  for (int q = 0; q < 4; ++q) {
    const int rr = (t >> 4) + q * 16;
    const int c4 = (t & 15) * 4;
    const float4 v = *(const float4*)&inb[(size_t)rr * S + c4];
    *(float4*)&tile[rr][c4] = v;
  }
  __syncthreads();
  #pragma unroll
  for (int q = 0; q < 4; ++q) {
    const int srow = (t >> 4) + q * 16;
    const int dc = (t & 15) * 4;
    ushort4 o;
    o.x = f2bf(tile[dc + 0][srow]);
    o.y = f2bf(tile[dc + 1][srow]);
    o.z = f2bf(tile[dc + 2][srow]);
    o.w = f2bf(tile[dc + 3][srow]);
    *(ushort4*)&fused[((size_t)b * S + s0 + srow) * 512 + d0 + dc] = o;
  }
}

// ---------------------------------------------------------------------------
// Kernel 4: convert the three weight matrices f32 -> bf16 (layout kept [O][K])
// ---------------------------------------------------------------------------
__global__ __launch_bounds__(256)
void convert_w_kernel(const float* __restrict__ w0, int n0, ushort* __restrict__ o0,
                      const float* __restrict__ w1, int n1, ushort* __restrict__ o1,
                      const float* __restrict__ w2, int n2, ushort* __restrict__ o2) {
  const int which = blockIdx.y;
  const float* src = which == 0 ? w0 : which == 1 ? w1 : w2;
  ushort* dst = which == 0 ? o0 : which == 1 ? o1 : o2;
  const int n = which == 0 ? n0 : which == 1 ? n1 : n2;
  const int i = (blockIdx.x * 256 + threadIdx.x) * 4;
  if (i < n) {
    const float4 v = *(const float4*)&src[i];
    ushort4 o;
    o.x = f2bf(v.x); o.y = f2bf(v.y); o.z = f2bf(v.z); o.w = f2bf(v.w);
    *(ushort4*)&dst[i] = o;
  }
}

// ---------------------------------------------------------------------------
// Kernel 5: bf16 MFMA GEMM.  out[b,o,s] = act( sum_k W[o,k] X[b,s,k] + bias[o] )
// W: bf16 [O][K] (k contiguous).  X: bf16 [B][S][K] (k contiguous).
// Block: 256 thr (4 waves), tile 128o x 128s; wave w: s-range [w*32, w*32+32).
// outMode 0: bf16 [B][S][ldOut] at column colOff (+optional ReLU)
// outMode 1: fp32 [B][O][S] (final output)
// ---------------------------------------------------------------------------
__global__ __launch_bounds__(256)
void gemm_bf16_kernel(const ushort* __restrict__ W, int K, int O,
                      const ushort* __restrict__ X,
                      const float* __restrict__ bias,
                      void* __restrict__ out, int outMode, int ldOut, int colOff,
                      int relu) {
  const int b  = blockIdx.z;
  const int s0 = blockIdx.x * 128;
  const int o0 = blockIdx.y * 128;
  const int t  = threadIdx.x;
  const int wave = t >> 6;
  const int lane = t & 63;
  const int l16 = lane & 15;
  const int quad = lane >> 4;

  // 80-byte row stride (40 ushorts): 16B-aligned rows, 2-way bank alias (free)
  __shared__ ushort Wt[128 * 40];
  __shared__ ushort Xt[128 * 40];
  __shared__ float biasS[128];

  if (t < 128) biasS[t] = bias[o0 + t];

  f32x4 acc[8][2];
  const f32x4 z = {0.f, 0.f, 0.f, 0.f};
  #pragma unroll
  for (int of = 0; of < 8; ++of) { acc[of][0] = z; acc[of][1] = z; }

  const ushort* Xb = X + (size_t)b * S * K;
  const int kg = t & 3;        // k-group: 8 bf16 each
  const int row = t >> 2;      // 0..63

  for (int c0 = 0; c0 < K; c0 += 32) {
    __syncthreads();
    #pragma unroll
    for (int q = 0; q < 2; ++q) {
      const int rr = row + 64 * q;
      const uint4 wv = *(const uint4*)&W[(size_t)(o0 + rr) * K + c0 + kg * 8];
      *(uint4*)&Wt[rr * 40 + kg * 8] = wv;
      const uint4 xv = *(const uint4*)&Xb[(size_t)(s0 + rr) * K + c0 + kg * 8];
      *(uint4*)&Xt[rr * 40 + kg * 8] = xv;
    }
    __syncthreads();

    bf16x8 bfr[2];
    #pragma unroll
    for (int sf = 0; sf < 2; ++sf)
      bfr[sf] = *(const bf16x8*)&Xt[(wave * 32 + sf * 16 + l16) * 40 + quad * 8];
    #pragma unroll
    for (int of = 0; of < 8; ++of) {
      const bf16x8 afr = *(const bf16x8*)&Wt[(of * 16 + l16) * 40 + quad * 8];
      acc[of][0] = __builtin_amdgcn_mfma_f32_16x16x32_bf16(afr, bfr[0], acc[of][0], 0, 0, 0);
      acc[of][1] = __builtin_amdgcn_mfma_f32_16x16x32_bf16(afr, bfr[1], acc[of][1], 0, 0, 0);
    }
  }

  // epilogue: lane holds D[o = of*16 + quad*4 + r][s = wave*32 + sf*16 + l16]
  if (outMode == 0) {
    ushort* ob = (ushort*)out;
    #pragma unroll
    for (int of = 0; of < 8; ++of) {
      #pragma unroll
      for (int sf = 0; sf < 2; ++sf) {
        const int s = s0 + wave * 32 + sf * 16 + l16;
        const int ol = of * 16 + quad * 4;
        float v0 = acc[of][sf].x + biasS[ol + 0];
        float v1 = acc[of][sf].y + biasS[ol + 1];
        float v2 = acc[of][sf].z + biasS[ol + 2];
        float v3 = acc[of][sf].w + biasS[ol + 3];
        if (relu) {
          v0 = fmaxf(v0, 0.f); v1 = fmaxf(v1, 0.f);
          v2 = fmaxf(v2, 0.f); v3 = fmaxf(v3, 0.f);
        }
        ushort4 st;
        st.x = f2bf(v0); st.y = f2bf(v1); st.z = f2bf(v2); st.w = f2bf(v3);
        *(ushort4*)&ob[((size_t)b * S + s) * ldOut + colOff + o0 + ol] = st;
      }
    }
  } else {
    float* o32 = (float*)out;
    #pragma unroll
    for (int of = 0; of < 8; ++of) {
      #pragma unroll
      for (int sf = 0; sf < 2; ++sf) {
        const int s = s0 + wave * 32 + sf * 16 + l16;
        const int ol = of * 16 + quad * 4;
        const float vr[4] = {acc[of][sf].x, acc[of][sf].y, acc[of][sf].z, acc[of][sf].w};
        #pragma unroll
        for (int r = 0; r < 4; ++r) {
          const int o = o0 + ol + r;
          o32[((size_t)b * O + o) * S + s] = vr[r] + biasS[ol + r];
        }
      }
    }
  }
}

}  // namespace

extern "C" void kernel_launch(void* const* d_in, const int* in_sizes, int n_in,
                              void* d_out, int out_size, void* d_ws, size_t ws_size,
                              hipStream_t stream) {
  const float* seed_xyz  = (const float*)d_in[0];   // [B,S,3]
  const float* p_last    = (const float*)d_in[1];   // [B,M,3]
  const float* f_last    = (const float*)d_in[2];   // [B,C,M]
  const float* seed_feat = (const float*)d_in[3];   // [B,D,S]
  const float* ln_gamma  = (const float*)d_in[4];   // [C]
  const float* ln_beta   = (const float*)d_in[5];   // [C]
  const float* proj_w    = (const float*)d_in[6];   // [D,C]
  const float* proj_b    = (const float*)d_in[7];   // [D]
  const float* mlp_w1    = (const float*)d_in[8];   // [512,512]
  const float* mlp_b1    = (const float*)d_in[9];   // [512]
  const float* mlp_w2    = (const float*)d_in[10];  // [256,512]
  const float* mlp_b2    = (const float*)d_in[11];  // [256]
  float* out = (float*)d_out;                       // [B,256,S] fp32

  // workspace layout:
  //   0      +64KB   idx [B*S] int
  //   64KB   +64KB   sortedIdx
  //   128KB  +64KB   sortedS
  //   256KB  +384KB  proj_w bf16 [256][768]
  //   640KB  +512KB  mlp_w1 bf16 [512][512]
  //   1152KB +256KB  mlp_w2 bf16 [256][512]
  //   2MB    +24MB   xln   bf16 [B][S][768]
  //   26MB   +16MB   fused bf16 [B][S][512]  (0:256 seed_feat^T, 256:512 proj)
  //   42MB   +16MB   h     bf16 [B][S][512]
  char* ws = (char*)d_ws;
  int*    idx   = (int*)(ws);
  int*    sIdx  = (int*)(ws + (64 << 10));
  int*    sS    = (int*)(ws + (128 << 10));
  ushort* wp_bf = (ushort*)(ws + (256 << 10));
  ushort* w1_bf = (ushort*)(ws + (640 << 10));
  ushort* w2_bf = (ushort*)(ws + (1152 << 10));
  ushort* xln   = (ushort*)(ws + (2ull << 20));
  ushort* fused = (ushort*)(ws + (26ull << 20));
  ushort* hbuf  = (ushort*)(ws + (42ull << 20));

  // 1) nearest neighbor + sort by idx
  nn_kernel<<<dim3(S / 16, B), 256, 0, stream>>>(seed_xyz, p_last, idx);
  sort_kernel<<<dim3(B), 512, 0, stream>>>(idx, sIdx, sS);

  // 2) gather + layernorm -> xln bf16 [B][S][768]
  gather_ln_kernel<<<dim3(S, B), 256, 0, stream>>>(f_last, sIdx, sS,
                                                   ln_gamma, ln_beta, xln);

  // 3) seed_features -> fused[:, :, 0:256] bf16 ; weights -> bf16
  transpose_sf_kernel<<<dim3(S / 64, D / 64, B), 256, 0, stream>>>(seed_feat, fused);
  convert_w_kernel<<<dim3(256, 3), 256, 0, stream>>>(
      proj_w, D * C, wp_bf, mlp_w1, 512 * 512, w1_bf, mlp_w2, 256 * 512, w2_bf);

  // 4) proj = relu(proj_w @ xln + b) -> fused[:, :, 256:512]
  gemm_bf16_kernel<<<dim3(S / 128, 256 / 128, B), 256, 0, stream>>>(
      wp_bf, C, 256, xln, proj_b, fused, 0, 512, 256, 1);

  // 5) h = relu(mlp_w1 @ fused + b1) -> hbuf [B][S][512]
  gemm_bf16_kernel<<<dim3(S / 128, 512 / 128, B), 256, 0, stream>>>(
      w1_bf, 512, 512, fused, mlp_b1, hbuf, 0, 512, 0, 1);

  // 6) out = mlp_w2 @ h + b2 -> fp32 [B][256][S]
  gemm_bf16_kernel<<<dim3(S / 128, 256 / 128, B), 256, 0, stream>>>(
      w2_bf, 512, 256, hbuf, mlp_b2, out, 1, 0, 0, 0);
}